// Round 1
// baseline (514.595 us; speedup 1.0000x reference)
//
#include <hip/hip_runtime.h>
#include <hip/hip_bf16.h>

// B=4, S=2048, D=1024, P=1024 causal self-attention, bf16 MFMA pipeline.
// Pipeline: cast x->bf16; transpose+cast W; QKV GEMMs; transpose V;
// per batch: scores GEMM (causal, fp32) -> softmax (fp32->bf16 P) -> PV GEMM.

#define BDIM 4
#define SDIM 2048
#define DDIM 1024
#define PDIM 1024

typedef __attribute__((ext_vector_type(8))) short bf16x8;
typedef __attribute__((ext_vector_type(4))) float f32x4;

// ---------- helpers ----------
__device__ __forceinline__ unsigned short f2bf(float f) {
    union { float f; unsigned int u; } v; v.f = f;
    unsigned int u = v.u;
    unsigned int r = (u + 0x7fffu + ((u >> 16) & 1u)) >> 16;
    return (unsigned short)r;
}

__device__ __forceinline__ void async16(const unsigned short* g, unsigned short* l) {
    __builtin_amdgcn_global_load_lds(
        (const __attribute__((address_space(1))) unsigned int*)g,
        (__attribute__((address_space(3))) unsigned int*)l,
        16, 0, 0);
}

__device__ __forceinline__ void storeC(float* C, size_t idx, float v) { C[idx] = v; }
__device__ __forceinline__ void storeC(unsigned short* C, size_t idx, float v) { C[idx] = f2bf(v); }

// ---------- cast x (fp32 -> bf16), 4 elems/thread ----------
__global__ __launch_bounds__(256) void cast_x_kernel(const float* __restrict__ x,
                                                     unsigned short* __restrict__ y) {
    int i = blockIdx.x * 256 + threadIdx.x;
    float4 v = ((const float4*)x)[i];
    ushort4 o;
    o.x = f2bf(v.x); o.y = f2bf(v.y); o.z = f2bf(v.z); o.w = f2bf(v.w);
    ((ushort4*)y)[i] = o;
}

// ---------- transpose + cast W (fp32 [K][N] -> bf16 [N][K]), z selects Wq/Wk/Wv ----------
__global__ __launch_bounds__(256) void transpose_cast_w(const float* __restrict__ W0,
                                                        const float* __restrict__ W1,
                                                        const float* __restrict__ W2,
                                                        unsigned short* __restrict__ T /* 3 outputs back-to-back */) {
    const float* W = (blockIdx.z == 0) ? W0 : (blockIdx.z == 1) ? W1 : W2;
    unsigned short* Tz = T + (size_t)blockIdx.z * DDIM * PDIM;
    __shared__ float t[32][33];
    int c0 = blockIdx.x * 32, r0 = blockIdx.y * 32;
    for (int i = threadIdx.y; i < 32; i += 8)
        t[i][threadIdx.x] = W[(size_t)(r0 + i) * PDIM + c0 + threadIdx.x];
    __syncthreads();
    for (int i = threadIdx.y; i < 32; i += 8)
        Tz[(size_t)(c0 + i) * DDIM + r0 + threadIdx.x] = f2bf(t[threadIdx.x][i]);
}

// ---------- bf16 transpose in [R][C] -> out [C][R], z-batched ----------
__global__ __launch_bounds__(256) void transpose_u16(const unsigned short* __restrict__ in,
                                                     unsigned short* __restrict__ out,
                                                     int R, int C) {
    __shared__ unsigned short t[32][33];
    size_t zoff = (size_t)blockIdx.z * R * C;
    in += zoff; out += zoff;
    int c0 = blockIdx.x * 32, r0 = blockIdx.y * 32;
    for (int i = threadIdx.y; i < 32; i += 8)
        t[i][threadIdx.x] = in[(size_t)(r0 + i) * C + c0 + threadIdx.x];
    __syncthreads();
    for (int i = threadIdx.y; i < 32; i += 8)
        out[(size_t)(c0 + i) * R + r0 + threadIdx.x] = t[threadIdx.x][i];
}

// ---------- m97-style GEMM: C[M][N] = alpha * A[M][K] @ Bt[N][K]^T ----------
// mode 0: plain.  mode 1: causal scores (skip tiles above diag, mask c>r with -1e30).
// mode 2: PV with K-loop clamped at row_tile+128 (P is zero beyond the diagonal).
template <typename CT>
__global__ __launch_bounds__(256) void gemm_bt(const unsigned short* __restrict__ A,
                                               const unsigned short* __restrict__ Bt,
                                               CT* __restrict__ C,
                                               int M, int N, int K, float alpha, int mode) {
    const int BM = 128, BN = 128, BK = 32;
    __shared__ __attribute__((aligned(16))) unsigned short As[BM * BK];
    __shared__ __attribute__((aligned(16))) unsigned short Bs[BN * BK];

    int tm = blockIdx.y * BM;
    int tn = blockIdx.x * BN;
    if (mode == 1 && tn > tm) return;              // fully-masked score tile
    int kend = (mode == 2) ? min(K, tm + BM) : K;  // causal K clamp for PV

    int tid  = threadIdx.x;
    int lane = tid & 63;
    int wave = tid >> 6;
    int wr   = (wave >> 1) * 64;
    int wc   = (wave & 1) * 64;
    int quad = lane >> 4;
    int l16  = lane & 15;

    f32x4 acc[4][4] = {};

    int arow = tid >> 2;            // 0..63
    int acol = (tid & 3) * 8;       // 0,8,16,24
    const unsigned short* Ag0 = A + (size_t)(tm + arow) * K + acol;
    const unsigned short* Ag1 = A + (size_t)(tm + 64 + arow) * K + acol;
    const unsigned short* Bg0 = Bt + (size_t)(tn + arow) * K + acol;
    const unsigned short* Bg1 = Bt + (size_t)(tn + 64 + arow) * K + acol;
    unsigned short* la0 = As + tid * 8;
    unsigned short* la1 = As + 2048 + tid * 8;
    unsigned short* lb0 = Bs + tid * 8;
    unsigned short* lb1 = Bs + 2048 + tid * 8;

    for (int k0 = 0; k0 < kend; k0 += BK) {
        async16(Ag0 + k0, la0);
        async16(Ag1 + k0, la1);
        async16(Bg0 + k0, lb0);
        async16(Bg1 + k0, lb1);
        __syncthreads();   // drains vmcnt (global_load_lds) before LDS reads

        bf16x8 af[4], bfr[4];
#pragma unroll
        for (int i = 0; i < 4; i++)
            af[i] = *(const bf16x8*)(As + (wr + i * 16 + l16) * BK + quad * 8);
#pragma unroll
        for (int j = 0; j < 4; j++)
            bfr[j] = *(const bf16x8*)(Bs + (wc + j * 16 + l16) * BK + quad * 8);
#pragma unroll
        for (int i = 0; i < 4; i++)
#pragma unroll
            for (int j = 0; j < 4; j++)
                acc[i][j] = __builtin_amdgcn_mfma_f32_16x16x32_bf16(af[i], bfr[j], acc[i][j], 0, 0, 0);
        __syncthreads();
    }

    // epilogue: C/D layout col=lane&15, row=quad*4+reg (verified m89/m91)
#pragma unroll
    for (int i = 0; i < 4; i++) {
        int r0 = tm + wr + i * 16 + quad * 4;
#pragma unroll
        for (int j = 0; j < 4; j++) {
            int c = tn + wc + j * 16 + l16;
#pragma unroll
            for (int rr = 0; rr < 4; rr++) {
                int r = r0 + rr;
                float v = acc[i][j][rr] * alpha;
                if (mode == 1 && c > r) v = -1e30f;
                storeC(C, (size_t)r * N + c, v);
            }
        }
    }
}

// ---------- row softmax with causal bound: S fp32 [S][S] -> P bf16 [S][S] ----------
__global__ __launch_bounds__(256) void softmax_causal(const float* __restrict__ Sb,
                                                      unsigned short* __restrict__ Pb,
                                                      int n) {
    int row = blockIdx.x;
    int valid = row + 1;
    const float* s = Sb + (size_t)row * n;
    int tid = threadIdx.x;
    __shared__ float red[4];

    float m = -1e30f;
    for (int j = tid; j < valid; j += 256) m = fmaxf(m, s[j]);
#pragma unroll
    for (int o = 32; o; o >>= 1) m = fmaxf(m, __shfl_xor(m, o, 64));
    if ((tid & 63) == 0) red[tid >> 6] = m;
    __syncthreads();
    m = fmaxf(fmaxf(red[0], red[1]), fmaxf(red[2], red[3]));
    __syncthreads();

    float l = 0.f;
    for (int j = tid; j < valid; j += 256) l += __expf(s[j] - m);
#pragma unroll
    for (int o = 32; o; o >>= 1) l += __shfl_xor(l, o, 64);
    if ((tid & 63) == 0) red[tid >> 6] = l;
    __syncthreads();
    l = red[0] + red[1] + red[2] + red[3];
    float inv = 1.0f / l;

    for (int j = tid; j < n; j += 256) {
        float p = (j < valid) ? __expf(s[j] - m) * inv : 0.f;
        Pb[(size_t)row * n + j] = f2bf(p);
    }
}

// ---------- host ----------
extern "C" void kernel_launch(void* const* d_in, const int* in_sizes, int n_in,
                              void* d_out, int out_size, void* d_ws, size_t ws_size,
                              hipStream_t stream) {
    const float* x  = (const float*)d_in[0];
    const float* Wq = (const float*)d_in[1];
    const float* Wk = (const float*)d_in[2];
    const float* Wv = (const float*)d_in[3];
    float* out = (float*)d_out;

    const size_t MS = (size_t)BDIM * SDIM;            // 8192
    char* ws = (char*)d_ws;
    size_t off = 0;
    unsigned short* Xb  = (unsigned short*)(ws + off); off += MS * DDIM * 2;            // 16 MB
    unsigned short* WT  = (unsigned short*)(ws + off); off += 3ull * DDIM * PDIM * 2;   // 6 MB (WqT,WkT,WvT)
    unsigned short* Q   = (unsigned short*)(ws + off); off += MS * PDIM * 2;            // 16 MB
    unsigned short* Kb  = (unsigned short*)(ws + off); off += MS * PDIM * 2;            // 16 MB
    unsigned short* V   = (unsigned short*)(ws + off); off += MS * PDIM * 2;            // 16 MB
    unsigned short* VT  = (unsigned short*)(ws + off); off += MS * PDIM * 2;            // 16 MB
    float*          Sb  = (float*)(ws + off);         off += (size_t)SDIM * SDIM * 4;   // 16 MB (per-batch)
    unsigned short* Pb  = (unsigned short*)(ws + off); off += (size_t)SDIM * SDIM * 2;  // 8 MB (per-batch)
    // total ~110 MB

    unsigned short* WqT = WT;
    unsigned short* WkT = WT + (size_t)DDIM * PDIM;
    unsigned short* WvT = WT + 2ull * DDIM * PDIM;

    // 1. cast x -> bf16
    cast_x_kernel<<<(MS * DDIM) / 1024, 256, 0, stream>>>(x, Xb);

    // 2. transpose+cast weights
    transpose_cast_w<<<dim3(PDIM / 32, DDIM / 32, 3), dim3(32, 8), 0, stream>>>(Wq, Wk, Wv, WT);

    // 3. QKV projections: [8192,1024] = Xb @ WT^T
    dim3 gqkv(PDIM / 128, MS / 128);
    gemm_bt<unsigned short><<<gqkv, 256, 0, stream>>>(Xb, WqT, Q,  (int)MS, PDIM, DDIM, 1.0f, 0);
    gemm_bt<unsigned short><<<gqkv, 256, 0, stream>>>(Xb, WkT, Kb, (int)MS, PDIM, DDIM, 1.0f, 0);
    gemm_bt<unsigned short><<<gqkv, 256, 0, stream>>>(Xb, WvT, V,  (int)MS, PDIM, DDIM, 1.0f, 0);

    // 4. transpose V per batch: [2048,1024] -> [1024,2048]
    transpose_u16<<<dim3(PDIM / 32, SDIM / 32, BDIM), dim3(32, 8), 0, stream>>>(V, VT, SDIM, PDIM);

    // 5. per batch: scores -> softmax -> PV
    const float alpha = 1.0f / 32.0f;  // 1/sqrt(P)
    for (int b = 0; b < BDIM; b++) {
        const unsigned short* Qb = Q  + (size_t)b * SDIM * PDIM;
        const unsigned short* Kbb = Kb + (size_t)b * SDIM * PDIM;
        const unsigned short* VTb = VT + (size_t)b * PDIM * SDIM;
        float* outb = out + (size_t)b * SDIM * PDIM;

        gemm_bt<float><<<dim3(SDIM / 128, SDIM / 128), 256, 0, stream>>>(
            Qb, Kbb, Sb, SDIM, SDIM, PDIM, alpha, 1);
        softmax_causal<<<SDIM, 256, 0, stream>>>(Sb, Pb, SDIM);
        gemm_bt<float><<<dim3(PDIM / 128, SDIM / 128), 256, 0, stream>>>(
            Pb, VTb, outb, SDIM, PDIM, SDIM, 1.0f, 2);
    }
}

// Round 2
// 301.100 us; speedup vs baseline: 1.7091x; 1.7091x over previous
//
#include <hip/hip_runtime.h>
#include <hip/hip_bf16.h>

// B=4, S=2048, D=1024, P=1024 causal self-attention, bf16 MFMA pipeline.
// Round 2: z-batched score/softmax/PV (fixes 1-block/CU latency binding),
// fused QKV GEMM (N=3072), bf16 scores + in-place softmax to fit ws.

#define BDIM 4
#define SDIM 2048
#define DDIM 1024
#define PDIM 1024

typedef __attribute__((ext_vector_type(8))) short bf16x8;
typedef __attribute__((ext_vector_type(4))) float f32x4;

// ---------- helpers ----------
__device__ __forceinline__ unsigned short f2bf(float f) {
    union { float f; unsigned int u; } v; v.f = f;
    unsigned int u = v.u;
    unsigned int r = (u + 0x7fffu + ((u >> 16) & 1u)) >> 16;
    return (unsigned short)r;
}

__device__ __forceinline__ float bf2f(unsigned short h) {
    union { unsigned int u; float f; } v;
    v.u = ((unsigned int)h) << 16;
    return v.f;
}

__device__ __forceinline__ void async16(const unsigned short* g, unsigned short* l) {
    __builtin_amdgcn_global_load_lds(
        (const __attribute__((address_space(1))) unsigned int*)g,
        (__attribute__((address_space(3))) unsigned int*)l,
        16, 0, 0);
}

__device__ __forceinline__ void storeC(float* C, size_t idx, float v) { C[idx] = v; }
__device__ __forceinline__ void storeC(unsigned short* C, size_t idx, float v) { C[idx] = f2bf(v); }

// ---------- cast x (fp32 -> bf16), 4 elems/thread ----------
__global__ __launch_bounds__(256) void cast_x_kernel(const float* __restrict__ x,
                                                     unsigned short* __restrict__ y) {
    int i = blockIdx.x * 256 + threadIdx.x;
    float4 v = ((const float4*)x)[i];
    ushort4 o;
    o.x = f2bf(v.x); o.y = f2bf(v.y); o.z = f2bf(v.z); o.w = f2bf(v.w);
    ((ushort4*)y)[i] = o;
}

// ---------- transpose + cast W (fp32 [K][N] -> bf16 [N][K]), z selects Wq/Wk/Wv ----------
__global__ __launch_bounds__(256) void transpose_cast_w(const float* __restrict__ W0,
                                                        const float* __restrict__ W1,
                                                        const float* __restrict__ W2,
                                                        unsigned short* __restrict__ T) {
    const float* W = (blockIdx.z == 0) ? W0 : (blockIdx.z == 1) ? W1 : W2;
    unsigned short* Tz = T + (size_t)blockIdx.z * DDIM * PDIM;
    __shared__ float t[32][33];
    int c0 = blockIdx.x * 32, r0 = blockIdx.y * 32;
    for (int i = threadIdx.y; i < 32; i += 8)
        t[i][threadIdx.x] = W[(size_t)(r0 + i) * PDIM + c0 + threadIdx.x];
    __syncthreads();
    for (int i = threadIdx.y; i < 32; i += 8)
        Tz[(size_t)(c0 + i) * DDIM + r0 + threadIdx.x] = f2bf(t[threadIdx.x][i]);
}

// ---------- bf16 transpose with strides: in [R][C] (ld=ldin) -> out [C][R] (ld=ldout) ----------
__global__ __launch_bounds__(256) void transpose_u16(const unsigned short* __restrict__ in,
                                                     int ldin, long long strideInZ,
                                                     unsigned short* __restrict__ out,
                                                     int ldout, long long strideOutZ) {
    __shared__ unsigned short t[32][33];
    in += (long long)blockIdx.z * strideInZ;
    out += (long long)blockIdx.z * strideOutZ;
    int c0 = blockIdx.x * 32, r0 = blockIdx.y * 32;
    for (int i = threadIdx.y; i < 32; i += 8)
        t[i][threadIdx.x] = in[(size_t)(r0 + i) * ldin + c0 + threadIdx.x];
    __syncthreads();
    for (int i = threadIdx.y; i < 32; i += 8)
        out[(size_t)(c0 + i) * ldout + r0 + threadIdx.x] = t[threadIdx.x][i];
}

// ---------- m97-style GEMM: C[M][N] = alpha * A[M][K] @ Bt[N][K]^T, z-batched ----------
// A/C use a split-pointer scheme: base = (z<2 ? X0 : X1) + (z&1)*stride.
// For a single contiguous buffer pass X1 = X0 + 2*stride.
// mode 0: plain.  mode 1: causal scores (skip tiles above diag, mask c>r).
// mode 2: PV with K-loop clamped at row_tile+BM (P is zero beyond diagonal).
template <typename CT>
__global__ __launch_bounds__(256) void gemm_bt(const unsigned short* __restrict__ A0,
                                               const unsigned short* __restrict__ A1,
                                               long long sA, int lda,
                                               const unsigned short* __restrict__ B0,
                                               long long sB, int ldb,
                                               CT* __restrict__ C0, CT* __restrict__ C1,
                                               long long sC, int ldc,
                                               int M, int N, int K, float alpha, int mode) {
    const int BM = 128, BN = 128, BK = 32;
    __shared__ __attribute__((aligned(16))) unsigned short As[BM * BK];
    __shared__ __attribute__((aligned(16))) unsigned short Bs[BN * BK];

    int tm = blockIdx.y * BM;
    int tn = blockIdx.x * BN;
    if (mode == 1 && tn > tm) return;              // fully-masked score tile
    int kend = (mode == 2) ? min(K, tm + BM) : K;  // causal K clamp for PV

    int z = blockIdx.z;
    const unsigned short* A = (z < 2 ? A0 : A1) + (long long)(z & 1) * sA;
    const unsigned short* Bt = B0 + (long long)z * sB;
    CT* C = (z < 2 ? C0 : C1) + (long long)(z & 1) * sC;

    int tid  = threadIdx.x;
    int lane = tid & 63;
    int wave = tid >> 6;
    int wr   = (wave >> 1) * 64;
    int wc   = (wave & 1) * 64;
    int quad = lane >> 4;
    int l16  = lane & 15;

    f32x4 acc[4][4] = {};

    int arow = tid >> 2;            // 0..63
    int acol = (tid & 3) * 8;       // 0,8,16,24
    const unsigned short* Ag0 = A + (size_t)(tm + arow) * lda + acol;
    const unsigned short* Ag1 = A + (size_t)(tm + 64 + arow) * lda + acol;
    const unsigned short* Bg0 = Bt + (size_t)(tn + arow) * ldb + acol;
    const unsigned short* Bg1 = Bt + (size_t)(tn + 64 + arow) * ldb + acol;
    unsigned short* la0 = As + tid * 8;
    unsigned short* la1 = As + 2048 + tid * 8;
    unsigned short* lb0 = Bs + tid * 8;
    unsigned short* lb1 = Bs + 2048 + tid * 8;

    for (int k0 = 0; k0 < kend; k0 += BK) {
        async16(Ag0 + k0, la0);
        async16(Ag1 + k0, la1);
        async16(Bg0 + k0, lb0);
        async16(Bg1 + k0, lb1);
        __syncthreads();   // drains vmcnt (global_load_lds) before LDS reads

        bf16x8 af[4], bfr[4];
#pragma unroll
        for (int i = 0; i < 4; i++)
            af[i] = *(const bf16x8*)(As + (wr + i * 16 + l16) * BK + quad * 8);
#pragma unroll
        for (int j = 0; j < 4; j++)
            bfr[j] = *(const bf16x8*)(Bs + (wc + j * 16 + l16) * BK + quad * 8);
#pragma unroll
        for (int i = 0; i < 4; i++)
#pragma unroll
            for (int j = 0; j < 4; j++)
                acc[i][j] = __builtin_amdgcn_mfma_f32_16x16x32_bf16(af[i], bfr[j], acc[i][j], 0, 0, 0);
        __syncthreads();
    }

    // epilogue: C/D layout col=lane&15, row=quad*4+reg
#pragma unroll
    for (int i = 0; i < 4; i++) {
        int r0 = tm + wr + i * 16 + quad * 4;
#pragma unroll
        for (int j = 0; j < 4; j++) {
            int c = tn + wc + j * 16 + l16;
#pragma unroll
            for (int rr = 0; rr < 4; rr++) {
                int r = r0 + rr;
                float v = acc[i][j][rr] * alpha;
                if (mode == 1 && c > r) v = -1e30f;
                storeC(C, (size_t)r * ldc + c, v);
            }
        }
    }
}

// ---------- in-place causal softmax on bf16 S: row-wise S -> P (same buffer) ----------
// grid (SDIM, BDIM); each thread owns 8 contiguous elems (reads->regs->writes, no hazard).
__global__ __launch_bounds__(256) void softmax_causal(unsigned short* __restrict__ S01,
                                                      unsigned short* __restrict__ S23,
                                                      long long sS) {
    int row = blockIdx.x;
    int b = blockIdx.y;
    unsigned short* srow = (b < 2 ? S01 : S23) + (long long)(b & 1) * sS + (size_t)row * SDIM;
    int tid = threadIdx.x;
    int j0 = tid * 8;
    int valid = row + 1;
    __shared__ float red[4];

    bf16x8 v8 = *(const bf16x8*)(srow + j0);
    float f[8];
#pragma unroll
    for (int i = 0; i < 8; i++) f[i] = bf2f((unsigned short)v8[i]);

    float m = -1e30f;
#pragma unroll
    for (int i = 0; i < 8; i++) if (j0 + i < valid) m = fmaxf(m, f[i]);
#pragma unroll
    for (int o = 32; o; o >>= 1) m = fmaxf(m, __shfl_xor(m, o, 64));
    if ((tid & 63) == 0) red[tid >> 6] = m;
    __syncthreads();
    m = fmaxf(fmaxf(red[0], red[1]), fmaxf(red[2], red[3]));
    __syncthreads();

    float e[8];
    float l = 0.f;
#pragma unroll
    for (int i = 0; i < 8; i++) {
        e[i] = (j0 + i < valid) ? __expf(f[i] - m) : 0.f;
        l += e[i];
    }
#pragma unroll
    for (int o = 32; o; o >>= 1) l += __shfl_xor(l, o, 64);
    if ((tid & 63) == 0) red[tid >> 6] = l;
    __syncthreads();
    l = red[0] + red[1] + red[2] + red[3];
    float inv = 1.0f / l;

    bf16x8 o8;
#pragma unroll
    for (int i = 0; i < 8; i++) o8[i] = (short)f2bf(e[i] * inv);
    *(bf16x8*)(srow + j0) = o8;
}

// ---------- host ----------
extern "C" void kernel_launch(void* const* d_in, const int* in_sizes, int n_in,
                              void* d_out, int out_size, void* d_ws, size_t ws_size,
                              hipStream_t stream) {
    const float* x  = (const float*)d_in[0];
    const float* Wq = (const float*)d_in[1];
    const float* Wk = (const float*)d_in[2];
    const float* Wv = (const float*)d_in[3];
    float* out = (float*)d_out;

    const size_t MS = (size_t)BDIM * SDIM;  // 8192
    const long long SS = (long long)SDIM * SDIM;       // per-batch score elems
    char* ws = (char*)d_ws;
    size_t off = 0;
    // S01 aliases Xb: Xb (16 MB) is dead after the QKV GEMM; score GEMM runs later.
    unsigned short* Xb   = (unsigned short*)(ws + off);
    unsigned short* S01  = Xb;                          off += MS * DDIM * 2;             // 16 MB
    unsigned short* WT   = (unsigned short*)(ws + off); off += 3ull * DDIM * PDIM * 2;    // 6 MB
    unsigned short* QKVf = (unsigned short*)(ws + off); off += MS * 3ull * PDIM * 2;      // 48 MB
    unsigned short* VT   = (unsigned short*)(ws + off); off += MS * PDIM * 2;             // 16 MB
    unsigned short* S23  = (unsigned short*)(ws + off); off += 2ull * SS * 2;             // 16 MB
    // total ~102 MB

    const int LQKV = 3 * PDIM;  // 3072 row stride of fused QKV output

    // 1. cast x -> bf16
    cast_x_kernel<<<(MS * DDIM) / 1024, 256, 0, stream>>>(x, Xb);

    // 2. transpose+cast weights (WqT/WkT/WvT back-to-back = Bt of the fused GEMM)
    transpose_cast_w<<<dim3(PDIM / 32, DDIM / 32, 3), dim3(32, 8), 0, stream>>>(Wq, Wk, Wv, WT);

    // 3. fused QKV projection: [8192,3072] = Xb @ WT^T   (1536 blocks)
    gemm_bt<unsigned short><<<dim3(LQKV / 128, MS / 128, 1), 256, 0, stream>>>(
        Xb, Xb, 0, DDIM, WT, 0, DDIM,
        QKVf, QKVf, 0, LQKV, (int)MS, LQKV, DDIM, 1.0f, 0);

    // 4. transpose V (strided view of QKVf) -> VT [B][P][S]
    transpose_u16<<<dim3(PDIM / 32, SDIM / 32, BDIM), dim3(32, 8), 0, stream>>>(
        QKVf + 2 * PDIM, LQKV, (long long)SDIM * LQKV,
        VT, SDIM, (long long)PDIM * SDIM);

    const long long sQK = (long long)SDIM * LQKV;  // per-batch stride within QKVf
    const float alpha = 1.0f / 32.0f;              // 1/sqrt(P)

    // 5. scores (all batches): S_b = alpha * Q_b @ K_b^T, causal, bf16 out (split S01/S23)
    gemm_bt<unsigned short><<<dim3(SDIM / 128, SDIM / 128, BDIM), 256, 0, stream>>>(
        QKVf, QKVf + 2 * sQK, sQK, LQKV,
        QKVf + PDIM, sQK, LQKV,
        S01, S23, SS, SDIM, SDIM, SDIM, PDIM, alpha, 1);

    // 6. in-place softmax (S -> P, bf16)
    softmax_causal<<<dim3(SDIM, BDIM), 256, 0, stream>>>(S01, S23, SS);

    // 7. PV (all batches): out_b = P_b @ VT_b^T   (split A pointers, causal K clamp)
    const long long sOut = (long long)SDIM * PDIM;
    gemm_bt<float><<<dim3(PDIM / 128, SDIM / 128, BDIM), 256, 0, stream>>>(
        S01, S23, SS, SDIM,
        VT, (long long)PDIM * SDIM, SDIM,
        out, out + 2 * sOut, sOut, PDIM, SDIM, PDIM, SDIM, 1.0f, 2);
}

// Round 3
// 270.158 us; speedup vs baseline: 1.9048x; 1.1145x over previous
//
#include <hip/hip_runtime.h>
#include <hip/hip_bf16.h>

// B=4, S=2048, D=1024, P=1024 causal self-attention, bf16 MFMA pipeline.
// Round 3: BK=64 GEMM core (half the barrier drains, 32 MFMA/wave per barrier
// pair) with XOR-swizzled LDS chunk placement (chunk c of row r at c^(r&7))
// to keep ds_read_b128 at the 8-bank-round structural floor.

#define BDIM 4
#define SDIM 2048
#define DDIM 1024
#define PDIM 1024

typedef __attribute__((ext_vector_type(8))) short bf16x8;
typedef __attribute__((ext_vector_type(4))) float f32x4;

// ---------- helpers ----------
__device__ __forceinline__ unsigned short f2bf(float f) {
    union { float f; unsigned int u; } v; v.f = f;
    unsigned int u = v.u;
    unsigned int r = (u + 0x7fffu + ((u >> 16) & 1u)) >> 16;
    return (unsigned short)r;
}

__device__ __forceinline__ float bf2f(unsigned short h) {
    union { unsigned int u; float f; } v;
    v.u = ((unsigned int)h) << 16;
    return v.f;
}

__device__ __forceinline__ void async16(const unsigned short* g, unsigned short* l) {
    __builtin_amdgcn_global_load_lds(
        (const __attribute__((address_space(1))) unsigned int*)g,
        (__attribute__((address_space(3))) unsigned int*)l,
        16, 0, 0);
}

__device__ __forceinline__ void storeC(float* C, size_t idx, float v) { C[idx] = v; }
__device__ __forceinline__ void storeC(unsigned short* C, size_t idx, float v) { C[idx] = f2bf(v); }

// ---------- cast x (fp32 -> bf16), 4 elems/thread ----------
__global__ __launch_bounds__(256) void cast_x_kernel(const float* __restrict__ x,
                                                     unsigned short* __restrict__ y) {
    int i = blockIdx.x * 256 + threadIdx.x;
    float4 v = ((const float4*)x)[i];
    ushort4 o;
    o.x = f2bf(v.x); o.y = f2bf(v.y); o.z = f2bf(v.z); o.w = f2bf(v.w);
    ((ushort4*)y)[i] = o;
}

// ---------- transpose + cast W (fp32 [K][N] -> bf16 [N][K]), z selects Wq/Wk/Wv ----------
__global__ __launch_bounds__(256) void transpose_cast_w(const float* __restrict__ W0,
                                                        const float* __restrict__ W1,
                                                        const float* __restrict__ W2,
                                                        unsigned short* __restrict__ T) {
    const float* W = (blockIdx.z == 0) ? W0 : (blockIdx.z == 1) ? W1 : W2;
    unsigned short* Tz = T + (size_t)blockIdx.z * DDIM * PDIM;
    __shared__ float t[32][33];
    int c0 = blockIdx.x * 32, r0 = blockIdx.y * 32;
    for (int i = threadIdx.y; i < 32; i += 8)
        t[i][threadIdx.x] = W[(size_t)(r0 + i) * PDIM + c0 + threadIdx.x];
    __syncthreads();
    for (int i = threadIdx.y; i < 32; i += 8)
        Tz[(size_t)(c0 + i) * DDIM + r0 + threadIdx.x] = f2bf(t[threadIdx.x][i]);
}

// ---------- bf16 transpose with strides: in [R][C] (ld=ldin) -> out [C][R] (ld=ldout) ----------
__global__ __launch_bounds__(256) void transpose_u16(const unsigned short* __restrict__ in,
                                                     int ldin, long long strideInZ,
                                                     unsigned short* __restrict__ out,
                                                     int ldout, long long strideOutZ) {
    __shared__ unsigned short t[32][33];
    in += (long long)blockIdx.z * strideInZ;
    out += (long long)blockIdx.z * strideOutZ;
    int c0 = blockIdx.x * 32, r0 = blockIdx.y * 32;
    for (int i = threadIdx.y; i < 32; i += 8)
        t[i][threadIdx.x] = in[(size_t)(r0 + i) * ldin + c0 + threadIdx.x];
    __syncthreads();
    for (int i = threadIdx.y; i < 32; i += 8)
        out[(size_t)(c0 + i) * ldout + r0 + threadIdx.x] = t[threadIdx.x][i];
}

// ---------- BK=64 GEMM: C[M][N] = alpha * A[M][K] @ Bt[N][K]^T, z-batched ----------
// LDS layout: row r (64 elems = 8 chunks of 8 elems); chunk c stored at
// position c ^ (r&7)  -> ds_read_b128 spreads over all 8 bank groups.
// A/C split-pointer scheme: base = (z<2 ? X0 : X1) + (z&1)*stride.
// mode 0: plain.  mode 1: causal scores (skip tiles above diag, mask c>r).
// mode 2: PV with K-loop clamped at row_tile+BM.
template <typename CT>
__global__ __launch_bounds__(256) void gemm_bt(const unsigned short* __restrict__ A0,
                                               const unsigned short* __restrict__ A1,
                                               long long sA, int lda,
                                               const unsigned short* __restrict__ B0,
                                               long long sB, int ldb,
                                               CT* __restrict__ C0, CT* __restrict__ C1,
                                               long long sC, int ldc,
                                               int M, int N, int K, float alpha, int mode) {
    const int BM = 128, BN = 128, BK = 64;
    __shared__ __attribute__((aligned(16))) unsigned short As[BM * BK];  // 16 KB
    __shared__ __attribute__((aligned(16))) unsigned short Bs[BN * BK];  // 16 KB

    int tm = blockIdx.y * BM;
    int tn = blockIdx.x * BN;
    if (mode == 1 && tn > tm) return;              // fully-masked score tile
    int kend = (mode == 2) ? min(K, tm + BM) : K;  // causal K clamp for PV

    int z = blockIdx.z;
    const unsigned short* A = (z < 2 ? A0 : A1) + (long long)(z & 1) * sA;
    const unsigned short* Bt = B0 + (long long)z * sB;
    CT* C = (z < 2 ? C0 : C1) + (long long)(z & 1) * sC;

    int tid  = threadIdx.x;
    int lane = tid & 63;
    int wave = tid >> 6;
    int wr   = (wave >> 1) * 64;
    int wc   = (wave & 1) * 64;
    int quad = lane >> 4;
    int l16  = lane & 15;
    int rsw  = l16 & 7;             // read-side swizzle key (row & 7)

    f32x4 acc[4][4] = {};

    // staging: thread -> (row = tid>>3 (+32/pass), stored chunk = tid&7)
    // source chunk = stored ^ (row&7); (row+32p)&7 invariant across passes.
    int srow = tid >> 3;            // 0..31
    int scol = ((tid & 7) ^ (srow & 7)) * 8;
    const unsigned short* Ag = A + (size_t)(tm + srow) * lda + scol;
    const unsigned short* Bg = Bt + (size_t)(tn + srow) * ldb + scol;
    unsigned short* la = As + tid * 8;
    unsigned short* lb = Bs + tid * 8;
    const size_t pA = (size_t)32 * lda;   // 32-row pass stride
    const size_t pB = (size_t)32 * ldb;

    for (int k0 = 0; k0 < kend; k0 += BK) {
        async16(Ag + k0, la);
        async16(Ag + k0 + pA, la + 2048);
        async16(Ag + k0 + 2 * pA, la + 4096);
        async16(Ag + k0 + 3 * pA, la + 6144);
        async16(Bg + k0, lb);
        async16(Bg + k0 + pB, lb + 2048);
        async16(Bg + k0 + 2 * pB, lb + 4096);
        async16(Bg + k0 + 3 * pB, lb + 6144);
        __syncthreads();   // drains vmcnt (global_load_lds) before LDS reads

#pragma unroll
        for (int s = 0; s < 2; s++) {
            int chunk = ((s * 4 + quad) ^ rsw) * 8;   // swizzled k-chunk offset
            bf16x8 af[4], bfr[4];
#pragma unroll
            for (int i = 0; i < 4; i++)
                af[i] = *(const bf16x8*)(As + (wr + i * 16 + l16) * BK + chunk);
#pragma unroll
            for (int j = 0; j < 4; j++)
                bfr[j] = *(const bf16x8*)(Bs + (wc + j * 16 + l16) * BK + chunk);
#pragma unroll
            for (int i = 0; i < 4; i++)
#pragma unroll
                for (int j = 0; j < 4; j++)
                    acc[i][j] = __builtin_amdgcn_mfma_f32_16x16x32_bf16(af[i], bfr[j], acc[i][j], 0, 0, 0);
        }
        __syncthreads();
    }

    // epilogue: C/D layout col=lane&15, row=quad*4+reg
#pragma unroll
    for (int i = 0; i < 4; i++) {
        int r0 = tm + wr + i * 16 + quad * 4;
#pragma unroll
        for (int j = 0; j < 4; j++) {
            int c = tn + wc + j * 16 + l16;
#pragma unroll
            for (int rr = 0; rr < 4; rr++) {
                int r = r0 + rr;
                float v = acc[i][j][rr] * alpha;
                if (mode == 1 && c > r) v = -1e30f;
                storeC(C, (size_t)r * ldc + c, v);
            }
        }
    }
}

// ---------- in-place causal softmax on bf16 S: row-wise S -> P (same buffer) ----------
__global__ __launch_bounds__(256) void softmax_causal(unsigned short* __restrict__ S01,
                                                      unsigned short* __restrict__ S23,
                                                      long long sS) {
    int row = blockIdx.x;
    int b = blockIdx.y;
    unsigned short* srow = (b < 2 ? S01 : S23) + (long long)(b & 1) * sS + (size_t)row * SDIM;
    int tid = threadIdx.x;
    int j0 = tid * 8;
    int valid = row + 1;
    __shared__ float red[4];

    bf16x8 v8 = *(const bf16x8*)(srow + j0);
    float f[8];
#pragma unroll
    for (int i = 0; i < 8; i++) f[i] = bf2f((unsigned short)v8[i]);

    float m = -1e30f;
#pragma unroll
    for (int i = 0; i < 8; i++) if (j0 + i < valid) m = fmaxf(m, f[i]);
#pragma unroll
    for (int o = 32; o; o >>= 1) m = fmaxf(m, __shfl_xor(m, o, 64));
    if ((tid & 63) == 0) red[tid >> 6] = m;
    __syncthreads();
    m = fmaxf(fmaxf(red[0], red[1]), fmaxf(red[2], red[3]));
    __syncthreads();

    float e[8];
    float l = 0.f;
#pragma unroll
    for (int i = 0; i < 8; i++) {
        e[i] = (j0 + i < valid) ? __expf(f[i] - m) : 0.f;
        l += e[i];
    }
#pragma unroll
    for (int o = 32; o; o >>= 1) l += __shfl_xor(l, o, 64);
    if ((tid & 63) == 0) red[tid >> 6] = l;
    __syncthreads();
    l = red[0] + red[1] + red[2] + red[3];
    float inv = 1.0f / l;

    bf16x8 o8;
#pragma unroll
    for (int i = 0; i < 8; i++) o8[i] = (short)f2bf(e[i] * inv);
    *(bf16x8*)(srow + j0) = o8;
}

// ---------- host ----------
extern "C" void kernel_launch(void* const* d_in, const int* in_sizes, int n_in,
                              void* d_out, int out_size, void* d_ws, size_t ws_size,
                              hipStream_t stream) {
    const float* x  = (const float*)d_in[0];
    const float* Wq = (const float*)d_in[1];
    const float* Wk = (const float*)d_in[2];
    const float* Wv = (const float*)d_in[3];
    float* out = (float*)d_out;

    const size_t MS = (size_t)BDIM * SDIM;  // 8192
    const long long SS = (long long)SDIM * SDIM;       // per-batch score elems
    char* ws = (char*)d_ws;
    size_t off = 0;
    // S01 aliases Xb: Xb (16 MB) is dead after the QKV GEMM; score GEMM runs later.
    unsigned short* Xb   = (unsigned short*)(ws + off);
    unsigned short* S01  = Xb;                          off += MS * DDIM * 2;             // 16 MB
    unsigned short* WT   = (unsigned short*)(ws + off); off += 3ull * DDIM * PDIM * 2;    // 6 MB
    unsigned short* QKVf = (unsigned short*)(ws + off); off += MS * 3ull * PDIM * 2;      // 48 MB
    unsigned short* VT   = (unsigned short*)(ws + off); off += MS * PDIM * 2;             // 16 MB
    unsigned short* S23  = (unsigned short*)(ws + off); off += 2ull * SS * 2;             // 16 MB
    // total ~102 MB

    const int LQKV = 3 * PDIM;  // 3072 row stride of fused QKV output

    // 1. cast x -> bf16
    cast_x_kernel<<<(MS * DDIM) / 1024, 256, 0, stream>>>(x, Xb);

    // 2. transpose+cast weights (WqT/WkT/WvT back-to-back = Bt of the fused GEMM)
    transpose_cast_w<<<dim3(PDIM / 32, DDIM / 32, 3), dim3(32, 8), 0, stream>>>(Wq, Wk, Wv, WT);

    // 3. fused QKV projection: [8192,3072] = Xb @ WT^T   (1536 blocks)
    gemm_bt<unsigned short><<<dim3(LQKV / 128, MS / 128, 1), 256, 0, stream>>>(
        Xb, Xb, 0, DDIM, WT, 0, DDIM,
        QKVf, QKVf, 0, LQKV, (int)MS, LQKV, DDIM, 1.0f, 0);

    // 4. transpose V (strided view of QKVf) -> VT [B][P][S]
    transpose_u16<<<dim3(PDIM / 32, SDIM / 32, BDIM), dim3(32, 8), 0, stream>>>(
        QKVf + 2 * PDIM, LQKV, (long long)SDIM * LQKV,
        VT, SDIM, (long long)PDIM * SDIM);

    const long long sQK = (long long)SDIM * LQKV;  // per-batch stride within QKVf
    const float alpha = 1.0f / 32.0f;              // 1/sqrt(P)

    // 5. scores (all batches): S_b = alpha * Q_b @ K_b^T, causal, bf16 out (split S01/S23)
    gemm_bt<unsigned short><<<dim3(SDIM / 128, SDIM / 128, BDIM), 256, 0, stream>>>(
        QKVf, QKVf + 2 * sQK, sQK, LQKV,
        QKVf + PDIM, sQK, LQKV,
        S01, S23, SS, SDIM, SDIM, SDIM, PDIM, alpha, 1);

    // 6. in-place softmax (S -> P, bf16)
    softmax_causal<<<dim3(SDIM, BDIM), 256, 0, stream>>>(S01, S23, SS);

    // 7. PV (all batches): out_b = P_b @ VT_b^T   (split A pointers, causal K clamp)
    const long long sOut = (long long)SDIM * PDIM;
    gemm_bt<float><<<dim3(PDIM / 128, SDIM / 128, BDIM), 256, 0, stream>>>(
        S01, S23, SS, SDIM,
        VT, (long long)PDIM * SDIM, SDIM,
        out, out + 2 * sOut, sOut, PDIM, SDIM, PDIM, SDIM, 1.0f, 2);
}

// Round 4
// 235.033 us; speedup vs baseline: 2.1895x; 1.1494x over previous
//
#include <hip/hip_runtime.h>
#include <hip/hip_bf16.h>

// B=4, S=2048, D=1024, P=1024 causal self-attention, bf16 MFMA pipeline.
// Round 4: compile-time-specialized GEMM (LDA/LDB/LDC/KMAX template params,
// fully unrolled K-loop -> loop-invariant LDS addresses, immediate global
// offsets), packed lower-triangle score grid, V-transpose fused into the
// QKV epilogue (separate contiguous Q/K buffers, VT written directly).

#define BDIM 4
#define SDIM 2048
#define DDIM 1024
#define PDIM 1024

typedef __attribute__((ext_vector_type(8))) short bf16x8;
typedef __attribute__((ext_vector_type(4))) float f32x4;

// ---------- helpers ----------
__device__ __forceinline__ unsigned short f2bf(float f) {
    union { float f; unsigned int u; } v; v.f = f;
    unsigned int u = v.u;
    unsigned int r = (u + 0x7fffu + ((u >> 16) & 1u)) >> 16;
    return (unsigned short)r;
}

__device__ __forceinline__ float bf2f(unsigned short h) {
    union { unsigned int u; float f; } v;
    v.u = ((unsigned int)h) << 16;
    return v.f;
}

__device__ __forceinline__ void async16(const unsigned short* g, unsigned short* l) {
    __builtin_amdgcn_global_load_lds(
        (const __attribute__((address_space(1))) unsigned int*)g,
        (__attribute__((address_space(3))) unsigned int*)l,
        16, 0, 0);
}

__device__ __forceinline__ void storeC(float* C, size_t idx, float v) { C[idx] = v; }
__device__ __forceinline__ void storeC(unsigned short* C, size_t idx, float v) { C[idx] = f2bf(v); }

// ---------- cast x (fp32 -> bf16), 4 elems/thread ----------
__global__ __launch_bounds__(256) void cast_x_kernel(const float* __restrict__ x,
                                                     unsigned short* __restrict__ y) {
    int i = blockIdx.x * 256 + threadIdx.x;
    float4 v = ((const float4*)x)[i];
    ushort4 o;
    o.x = f2bf(v.x); o.y = f2bf(v.y); o.z = f2bf(v.z); o.w = f2bf(v.w);
    ((ushort4*)y)[i] = o;
}

// ---------- transpose + cast W (fp32 [K][N] -> bf16 [N][K]), z selects Wq/Wk/Wv ----------
__global__ __launch_bounds__(256) void transpose_cast_w(const float* __restrict__ W0,
                                                        const float* __restrict__ W1,
                                                        const float* __restrict__ W2,
                                                        unsigned short* __restrict__ T) {
    const float* W = (blockIdx.z == 0) ? W0 : (blockIdx.z == 1) ? W1 : W2;
    unsigned short* Tz = T + (size_t)blockIdx.z * DDIM * PDIM;
    __shared__ float t[32][33];
    int c0 = blockIdx.x * 32, r0 = blockIdx.y * 32;
    for (int i = threadIdx.y; i < 32; i += 8)
        t[i][threadIdx.x] = W[(size_t)(r0 + i) * PDIM + c0 + threadIdx.x];
    __syncthreads();
    for (int i = threadIdx.y; i < 32; i += 8)
        Tz[(size_t)(c0 + i) * DDIM + r0 + threadIdx.x] = f2bf(t[threadIdx.x][i]);
}

// ---------- specialized BK=64 GEMM: C[M][N] = alpha * A[M][K] @ Bt[N][K]^T ----------
// XOR-swizzled LDS (chunk c of row r at c^(r&7)) -> conflict-free ds_read_b128.
// MODE 0: fused QKV. tn<1024 -> Q (C0), 1024..2047 -> Kb, >=2048 -> VT
//         (written TRANSPOSED via LDS staging). grid (24,64,1).
// MODE 1: causal scores, packed lower-triangle grid (136,1,B); bf16 out,
//         cols > row masked to -1e30.
// MODE 2: PV, K-loop clamped at tm+BM (P zero beyond diagonal). f32 out.
// z batching: A=(z<2?A0:A1)+(z&1)*sA, Bt=B0+z*sB, C=(z<2?C0:C1)+(z&1)*sC.
template <int LDA, int LDB, int LDC, int KMAX, int MODE, typename CT>
__global__ __launch_bounds__(256) void gemm_bt(
    const unsigned short* __restrict__ A0, const unsigned short* __restrict__ A1,
    long long sA,
    const unsigned short* __restrict__ B0, long long sB,
    CT* __restrict__ C0, CT* __restrict__ C1, long long sC,
    unsigned short* __restrict__ Kb, unsigned short* __restrict__ VT,
    float alpha) {
    const int BM = 128, BN = 128, BK = 64;
    __shared__ __attribute__((aligned(16))) unsigned short smem[BM * BK + BN * BK];  // 32 KB
    unsigned short* As = smem;
    unsigned short* Bs = smem + BM * BK;

    int tm, tn;
    if (MODE == 1) {
        // packed lower-triangle decode: blockIdx.x in [0,136)
        int i = blockIdx.x;
        int t = (int)((sqrtf(8.f * i + 1.f) - 1.f) * 0.5f);
        if ((t + 1) * (t + 2) / 2 <= i) t++;
        if (t * (t + 1) / 2 > i) t--;
        tm = t * BM;
        tn = (i - t * (t + 1) / 2) * BN;
    } else {
        tm = blockIdx.y * BM;
        tn = blockIdx.x * BN;
    }
    int kend = (MODE == 2) ? min(KMAX, tm + BM) : KMAX;

    int z = blockIdx.z;
    const unsigned short* A = (z < 2 ? A0 : A1) + (long long)(z & 1) * sA;
    const unsigned short* Bt = B0 + (long long)z * sB;
    CT* C = (z < 2 ? C0 : C1) + (long long)(z & 1) * sC;

    int tid  = threadIdx.x;
    int lane = tid & 63;
    int wave = tid >> 6;
    int wr   = (wave >> 1) * 64;
    int wc   = (wave & 1) * 64;
    int quad = lane >> 4;
    int l16  = lane & 15;
    int rsw  = l16 & 7;             // read-side swizzle key

    f32x4 acc[4][4] = {};

    // staging: thread -> (row = tid>>3 (+32/pass), stored chunk = tid&7)
    int srow = tid >> 3;
    int scol = ((tid & 7) ^ (srow & 7)) * 8;
    const unsigned short* Ag = A + (size_t)(tm + srow) * LDA + scol;
    const unsigned short* Bg = Bt + (size_t)(tn + srow) * LDB + scol;
    unsigned short* la = As + tid * 8;
    unsigned short* lb = Bs + tid * 8;

    auto kstep = [&](int k0) {
        async16(Ag + k0, la);
        async16(Ag + k0 + 32 * LDA, la + 2048);
        async16(Ag + k0 + 64 * LDA, la + 4096);
        async16(Ag + k0 + 96 * LDA, la + 6144);
        async16(Bg + k0, lb);
        async16(Bg + k0 + 32 * LDB, lb + 2048);
        async16(Bg + k0 + 64 * LDB, lb + 4096);
        async16(Bg + k0 + 96 * LDB, lb + 6144);
        __syncthreads();   // drains vmcnt before LDS reads

#pragma unroll
        for (int s = 0; s < 2; s++) {
            int chunk = ((s * 4 + quad) ^ rsw) * 8;
            bf16x8 af[4], bfr[4];
#pragma unroll
            for (int i = 0; i < 4; i++)
                af[i] = *(const bf16x8*)(As + (wr + i * 16 + l16) * BK + chunk);
#pragma unroll
            for (int j = 0; j < 4; j++)
                bfr[j] = *(const bf16x8*)(Bs + (wc + j * 16 + l16) * BK + chunk);
#pragma unroll
            for (int i = 0; i < 4; i++)
#pragma unroll
                for (int j = 0; j < 4; j++)
                    acc[i][j] = __builtin_amdgcn_mfma_f32_16x16x32_bf16(af[i], bfr[j], acc[i][j], 0, 0, 0);
        }
        __syncthreads();
    };

    if constexpr (MODE != 2) {
#pragma unroll
        for (int k0 = 0; k0 < KMAX; k0 += BK) kstep(k0);
    } else {
        for (int k0 = 0; k0 < kend; k0 += 2 * BK) { kstep(k0); kstep(k0 + BK); }
    }

    // ---------------- epilogue (C/D layout: col=lane&15, row=quad*4+reg) ----------------
    if constexpr (MODE == 0) {
        if (tn < 2048) {
            unsigned short* D = (tn < 1024 ? (unsigned short*)C0 : Kb);
            int cbase = tn & 1023;
#pragma unroll
            for (int i = 0; i < 4; i++) {
                int r0 = tm + wr + i * 16 + quad * 4;
#pragma unroll
                for (int j = 0; j < 4; j++) {
                    int c = cbase + wc + j * 16 + l16;
#pragma unroll
                    for (int rr = 0; rr < 4; rr++)
                        D[(size_t)(r0 + rr) * 1024 + c] = f2bf(acc[i][j][rr]);
                }
            }
        } else {
            // V region: transposed write via LDS (4 passes of 32 p-columns)
            int b = tm >> 11;
            int s0 = tm & 2047;
            unsigned short* VTb = VT + (size_t)b * (PDIM * SDIM)
                                     + (size_t)(tn - 2048) * SDIM + s0;
            const int TP = 136;
            unsigned short* T = smem;  // 32 x 136 shorts, reuses dead tile buffer
#pragma unroll
            for (int p = 0; p < 4; p++) {
                int jbase = -1;
                if (wc == 0 && p == 0) jbase = 0;
                if (wc == 0 && p == 1) jbase = 2;
                if (wc == 64 && p == 2) jbase = 0;
                if (wc == 64 && p == 3) jbase = 2;
                if (jbase >= 0) {
#pragma unroll
                    for (int jj = 0; jj < 2; jj++) {
                        int j = jbase + jj;
                        int c = (wc + j * 16 + l16) - 32 * p;  // 0..31
#pragma unroll
                        for (int i = 0; i < 4; i++) {
                            int r = wr + i * 16 + quad * 4;
                            ushort4 w;
                            w.x = f2bf(acc[i][j][0]); w.y = f2bf(acc[i][j][1]);
                            w.z = f2bf(acc[i][j][2]); w.w = f2bf(acc[i][j][3]);
                            *(ushort4*)(T + c * TP + r) = w;
                        }
                    }
                }
                __syncthreads();
                {
                    int lr = tid >> 3;          // 0..31
                    int ck = (tid & 7) * 16;    // 0..112
                    bf16x8 u0 = *(const bf16x8*)(T + lr * TP + ck);
                    bf16x8 u1 = *(const bf16x8*)(T + lr * TP + ck + 8);
                    unsigned short* dst = VTb + (size_t)(32 * p + lr) * SDIM + ck;
                    *(bf16x8*)(dst) = u0;
                    *(bf16x8*)(dst + 8) = u1;
                }
                __syncthreads();
            }
        }
    } else {
#pragma unroll
        for (int i = 0; i < 4; i++) {
            int r0 = tm + wr + i * 16 + quad * 4;
#pragma unroll
            for (int j = 0; j < 4; j++) {
                int c = tn + wc + j * 16 + l16;
#pragma unroll
                for (int rr = 0; rr < 4; rr++) {
                    int r = r0 + rr;
                    float v = acc[i][j][rr] * alpha;
                    if (MODE == 1 && c > r) v = -1e30f;
                    storeC(C, (size_t)r * LDC + c, v);
                }
            }
        }
    }
}

// ---------- in-place causal softmax on bf16 S: row-wise S -> P (same buffer) ----------
__global__ __launch_bounds__(256) void softmax_causal(unsigned short* __restrict__ S01,
                                                      unsigned short* __restrict__ S23,
                                                      long long sS) {
    int row = blockIdx.x;
    int b = blockIdx.y;
    unsigned short* srow = (b < 2 ? S01 : S23) + (long long)(b & 1) * sS + (size_t)row * SDIM;
    int tid = threadIdx.x;
    int j0 = tid * 8;
    int valid = row + 1;
    __shared__ float red[4];

    bf16x8 v8 = *(const bf16x8*)(srow + j0);
    float f[8];
#pragma unroll
    for (int i = 0; i < 8; i++) f[i] = bf2f((unsigned short)v8[i]);

    float m = -1e30f;
#pragma unroll
    for (int i = 0; i < 8; i++) if (j0 + i < valid) m = fmaxf(m, f[i]);
#pragma unroll
    for (int o = 32; o; o >>= 1) m = fmaxf(m, __shfl_xor(m, o, 64));
    if ((tid & 63) == 0) red[tid >> 6] = m;
    __syncthreads();
    m = fmaxf(fmaxf(red[0], red[1]), fmaxf(red[2], red[3]));
    __syncthreads();

    float e[8];
    float l = 0.f;
#pragma unroll
    for (int i = 0; i < 8; i++) {
        e[i] = (j0 + i < valid) ? __expf(f[i] - m) : 0.f;
        l += e[i];
    }
#pragma unroll
    for (int o = 32; o; o >>= 1) l += __shfl_xor(l, o, 64);
    if ((tid & 63) == 0) red[tid >> 6] = l;
    __syncthreads();
    l = red[0] + red[1] + red[2] + red[3];
    float inv = 1.0f / l;

    bf16x8 o8;
#pragma unroll
    for (int i = 0; i < 8; i++) o8[i] = (short)f2bf(e[i] * inv);
    *(bf16x8*)(srow + j0) = o8;
}

// ---------- host ----------
extern "C" void kernel_launch(void* const* d_in, const int* in_sizes, int n_in,
                              void* d_out, int out_size, void* d_ws, size_t ws_size,
                              hipStream_t stream) {
    const float* x  = (const float*)d_in[0];
    const float* Wq = (const float*)d_in[1];
    const float* Wk = (const float*)d_in[2];
    const float* Wv = (const float*)d_in[3];
    float* out = (float*)d_out;

    const size_t MS = (size_t)BDIM * SDIM;        // 8192
    const long long SS = (long long)SDIM * SDIM;  // per-batch score elems
    char* ws = (char*)d_ws;
    size_t off = 0;
    // S01 aliases Xb (Xb dead after QKV GEMM).
    unsigned short* Xb   = (unsigned short*)(ws + off);
    unsigned short* S01  = Xb;                          off += MS * DDIM * 2;           // 16 MB
    unsigned short* WT   = (unsigned short*)(ws + off); off += 3ull * DDIM * PDIM * 2;  // 6 MB
    unsigned short* Q    = (unsigned short*)(ws + off); off += MS * PDIM * 2;           // 16 MB
    unsigned short* Kb   = (unsigned short*)(ws + off); off += MS * PDIM * 2;           // 16 MB
    unsigned short* VT   = (unsigned short*)(ws + off); off += MS * PDIM * 2;           // 16 MB
    unsigned short* S23  = (unsigned short*)(ws + off); off += 2ull * SS * 2;           // 16 MB
    // total ~86 MB

    // 1. cast x -> bf16
    cast_x_kernel<<<(MS * DDIM) / 1024, 256, 0, stream>>>(x, Xb);

    // 2. transpose+cast weights (WqT/WkT/WvT back-to-back)
    transpose_cast_w<<<dim3(PDIM / 32, DDIM / 32, 3), dim3(32, 8), 0, stream>>>(Wq, Wk, Wv, WT);

    // 3. fused QKV projection -> Q, Kb, VT(transposed)   (1536 blocks)
    gemm_bt<DDIM, DDIM, PDIM, DDIM, 0, unsigned short>
        <<<dim3(3 * PDIM / 128, MS / 128, 1), 256, 0, stream>>>(
        Xb, Xb, 0, WT, 0, Q, Q, 0, Kb, VT, 1.0f);

    const long long sQ = (long long)SDIM * PDIM;   // per-batch Q/K/VT stride
    const float alpha = 1.0f / 32.0f;              // 1/sqrt(P)

    // 4. scores: packed lower-triangle grid (136 tiles) x 4 batches
    gemm_bt<PDIM, PDIM, SDIM, PDIM, 1, unsigned short>
        <<<dim3(136, 1, BDIM), 256, 0, stream>>>(
        Q, Q + 2 * sQ, sQ, Kb, sQ, S01, S23, SS, nullptr, nullptr, alpha);

    // 5. in-place softmax (S -> P, bf16)
    softmax_causal<<<dim3(SDIM, BDIM), 256, 0, stream>>>(S01, S23, SS);

    // 6. PV: out_b = P_b @ VT_b^T with causal K clamp
    const long long sOut = (long long)SDIM * PDIM;
    gemm_bt<SDIM, SDIM, PDIM, SDIM, 2, float>
        <<<dim3(PDIM / 128, SDIM / 128, BDIM), 256, 0, stream>>>(
        S01, S23, SS, VT, sQ, out, out + 2 * sOut, sOut, nullptr, nullptr, 1.0f);
}

// Round 5
// 232.465 us; speedup vs baseline: 2.2136x; 1.0111x over previous
//
#include <hip/hip_runtime.h>
#include <hip/hip_bf16.h>

// B=4, S=2048, D=1024, P=1024 causal self-attention, bf16 MFMA pipeline.
// Round 5: ping-pong double-buffered K-loop (loads for tile k+1 in flight
// across tile k's MFMA section; one barrier per kstep), fused prep kernel
// (cast + W transpose), softmax reads valid chunks only / writes zeros only
// to the next 128-boundary, score epilogue skips masked stores.

#define BDIM 4
#define SDIM 2048
#define DDIM 1024
#define PDIM 1024

typedef __attribute__((ext_vector_type(8))) short bf16x8;
typedef __attribute__((ext_vector_type(4))) float f32x4;

// ---------- helpers ----------
__device__ __forceinline__ unsigned short f2bf(float f) {
    union { float f; unsigned int u; } v; v.f = f;
    unsigned int u = v.u;
    unsigned int r = (u + 0x7fffu + ((u >> 16) & 1u)) >> 16;
    return (unsigned short)r;
}

__device__ __forceinline__ float bf2f(unsigned short h) {
    union { unsigned int u; float f; } v;
    v.u = ((unsigned int)h) << 16;
    return v.f;
}

__device__ __forceinline__ void async16(const unsigned short* g, unsigned short* l) {
    __builtin_amdgcn_global_load_lds(
        (const __attribute__((address_space(1))) unsigned int*)g,
        (__attribute__((address_space(3))) unsigned int*)l,
        16, 0, 0);
}

__device__ __forceinline__ void storeC(float* C, size_t idx, float v) { C[idx] = v; }
__device__ __forceinline__ void storeC(unsigned short* C, size_t idx, float v) { C[idx] = f2bf(v); }

// ---------- fused prep: cast x (fp32->bf16) + transpose/cast W ----------
// blocks [0,4096): cast 8 elems/thread.  blocks [4096,7168): W tiles.
__global__ __launch_bounds__(256) void prep_kernel(const float* __restrict__ x,
                                                   const float* __restrict__ W0,
                                                   const float* __restrict__ W1,
                                                   const float* __restrict__ W2,
                                                   unsigned short* __restrict__ Xb,
                                                   unsigned short* __restrict__ WT) {
    int bid = blockIdx.x;
    if (bid < 4096) {
        size_t i = (size_t)bid * 256 + threadIdx.x;
        float4 a = ((const float4*)x)[2 * i];
        float4 b = ((const float4*)x)[2 * i + 1];
        bf16x8 o;
        o[0] = (short)f2bf(a.x); o[1] = (short)f2bf(a.y);
        o[2] = (short)f2bf(a.z); o[3] = (short)f2bf(a.w);
        o[4] = (short)f2bf(b.x); o[5] = (short)f2bf(b.y);
        o[6] = (short)f2bf(b.z); o[7] = (short)f2bf(b.w);
        ((bf16x8*)Xb)[i] = o;
    } else {
        int idx = bid - 4096;
        int wz = idx >> 10;
        int t = idx & 1023;
        const float* W = (wz == 0) ? W0 : (wz == 1) ? W1 : W2;
        unsigned short* Tz = WT + (size_t)wz * DDIM * PDIM;
        __shared__ float tle[32][33];
        int c0 = (t & 31) * 32, r0 = (t >> 5) * 32;
        int tx = threadIdx.x & 31, ty = threadIdx.x >> 5;
        for (int i = ty; i < 32; i += 8)
            tle[i][tx] = W[(size_t)(r0 + i) * PDIM + c0 + tx];
        __syncthreads();
        for (int i = ty; i < 32; i += 8)
            Tz[(size_t)(c0 + i) * DDIM + r0 + tx] = f2bf(tle[tx][i]);
    }
}

// ---------- dbuf BK=64 GEMM: C[M][N] = alpha * A[M][K] @ Bt[N][K]^T ----------
// XOR-swizzled LDS (chunk c of row r at c^(r&7)) -> conflict-free ds_read_b128.
// Ping-pong: loads for kstep i+1 issued before compute of kstep i; 1 barrier/kstep.
// MODE 0: fused QKV (tn<1024 -> Q, <2048 -> Kb, else VT transposed via LDS).
// MODE 1: causal scores, packed lower-triangle grid; skips masked stores.
// MODE 2: PV, K clamped at tm+BM.
template <int LDA, int LDB, int LDC, int KMAX, int MODE, typename CT>
__global__ __launch_bounds__(256) void gemm_bt(
    const unsigned short* __restrict__ A0, const unsigned short* __restrict__ A1,
    long long sA,
    const unsigned short* __restrict__ B0, long long sB,
    CT* __restrict__ C0, CT* __restrict__ C1, long long sC,
    unsigned short* __restrict__ Kb, unsigned short* __restrict__ VT,
    float alpha) {
    const int BM = 128, BN = 128, BK = 64;
    const int BUF = BM * BK + BN * BK;  // 16384 shorts per buffer
    __shared__ __attribute__((aligned(16))) unsigned short smem[2 * BUF];  // 64 KB

    int tm, tn;
    if (MODE == 1) {
        int i = blockIdx.x;
        int t = (int)((sqrtf(8.f * i + 1.f) - 1.f) * 0.5f);
        if ((t + 1) * (t + 2) / 2 <= i) t++;
        if (t * (t + 1) / 2 > i) t--;
        tm = t * BM;
        tn = (i - t * (t + 1) / 2) * BN;
    } else {
        tm = blockIdx.y * BM;
        tn = blockIdx.x * BN;
    }
    int kend = (MODE == 2) ? min(KMAX, tm + BM) : KMAX;

    int z = blockIdx.z;
    const unsigned short* A = (z < 2 ? A0 : A1) + (long long)(z & 1) * sA;
    const unsigned short* Bt = B0 + (long long)z * sB;
    CT* C = (z < 2 ? C0 : C1) + (long long)(z & 1) * sC;

    int tid  = threadIdx.x;
    int lane = tid & 63;
    int wave = tid >> 6;
    int wr   = (wave >> 1) * 64;
    int wc   = (wave & 1) * 64;
    int quad = lane >> 4;
    int l16  = lane & 15;
    int rsw  = l16 & 7;

    f32x4 acc[4][4] = {};

    int srow = tid >> 3;
    int scol = ((tid & 7) ^ (srow & 7)) * 8;
    const unsigned short* Ag = A + (size_t)(tm + srow) * LDA + scol;
    const unsigned short* Bg = Bt + (size_t)(tn + srow) * LDB + scol;

    auto issue = [&](int k0, int buf) {
        unsigned short* la = smem + buf * BUF + tid * 8;
        unsigned short* lb = la + BM * BK;
        async16(Ag + k0, la);
        async16(Ag + k0 + 32 * LDA, la + 2048);
        async16(Ag + k0 + 64 * LDA, la + 4096);
        async16(Ag + k0 + 96 * LDA, la + 6144);
        async16(Bg + k0, lb);
        async16(Bg + k0 + 32 * LDB, lb + 2048);
        async16(Bg + k0 + 64 * LDB, lb + 4096);
        async16(Bg + k0 + 96 * LDB, lb + 6144);
    };

    auto compute = [&](int buf) {
        const unsigned short* As = smem + buf * BUF;
        const unsigned short* Bs = As + BM * BK;
#pragma unroll
        for (int s = 0; s < 2; s++) {
            int chunk = ((s * 4 + quad) ^ rsw) * 8;
            bf16x8 af[4], bfr[4];
#pragma unroll
            for (int i = 0; i < 4; i++)
                af[i] = *(const bf16x8*)(As + (wr + i * 16 + l16) * BK + chunk);
#pragma unroll
            for (int j = 0; j < 4; j++)
                bfr[j] = *(const bf16x8*)(Bs + (wc + j * 16 + l16) * BK + chunk);
#pragma unroll
            for (int i = 0; i < 4; i++)
#pragma unroll
                for (int j = 0; j < 4; j++)
                    acc[i][j] = __builtin_amdgcn_mfma_f32_16x16x32_bf16(af[i], bfr[j], acc[i][j], 0, 0, 0);
        }
    };

    if constexpr (MODE != 2) {
        constexpr int NS = KMAX / BK;
        issue(0, 0);
#pragma unroll
        for (int i = 0; i < NS; i++) {
            __syncthreads();                        // drains buf[i&1] loads (in flight since last kstep)
            if (i + 1 < NS) issue((i + 1) * BK, (i + 1) & 1);
            compute(i & 1);
        }
    } else {
        int ns = kend / BK;
        issue(0, 0);
        for (int i = 0; i < ns; i++) {
            __syncthreads();
            if (i + 1 < ns) issue((i + 1) * BK, (i + 1) & 1);
            compute(i & 1);
        }
    }

    // ---------------- epilogue (C/D layout: col=lane&15, row=quad*4+reg) ----------------
    if constexpr (MODE == 0) {
        if (tn < 2048) {
            unsigned short* D = (tn < 1024 ? (unsigned short*)C0 : Kb);
            int cbase = tn & 1023;
#pragma unroll
            for (int i = 0; i < 4; i++) {
                int r0 = tm + wr + i * 16 + quad * 4;
#pragma unroll
                for (int j = 0; j < 4; j++) {
                    int c = cbase + wc + j * 16 + l16;
#pragma unroll
                    for (int rr = 0; rr < 4; rr++)
                        D[(size_t)(r0 + rr) * 1024 + c] = f2bf(acc[i][j][rr]);
                }
            }
        } else {
            // V region: transposed write via LDS (4 passes of 32 p-columns)
            int b = tm >> 11;
            int s0 = tm & 2047;
            unsigned short* VTb = VT + (size_t)b * (PDIM * SDIM)
                                     + (size_t)(tn - 2048) * SDIM + s0;
            const int TP = 136;
            unsigned short* T = smem;  // reuses buf0 (disjoint from any live reads)
            __syncthreads();
#pragma unroll
            for (int p = 0; p < 4; p++) {
                int jbase = -1;
                if (wc == 0 && p == 0) jbase = 0;
                if (wc == 0 && p == 1) jbase = 2;
                if (wc == 64 && p == 2) jbase = 0;
                if (wc == 64 && p == 3) jbase = 2;
                if (jbase >= 0) {
#pragma unroll
                    for (int jj = 0; jj < 2; jj++) {
                        int j = jbase + jj;
                        int c = (wc + j * 16 + l16) - 32 * p;  // 0..31
#pragma unroll
                        for (int i = 0; i < 4; i++) {
                            int r = wr + i * 16 + quad * 4;
                            ushort4 w;
                            w.x = f2bf(acc[i][j][0]); w.y = f2bf(acc[i][j][1]);
                            w.z = f2bf(acc[i][j][2]); w.w = f2bf(acc[i][j][3]);
                            *(ushort4*)(T + c * TP + r) = w;
                        }
                    }
                }
                __syncthreads();
                {
                    int lr = tid >> 3;
                    int ck = (tid & 7) * 16;
                    bf16x8 u0 = *(const bf16x8*)(T + lr * TP + ck);
                    bf16x8 u1 = *(const bf16x8*)(T + lr * TP + ck + 8);
                    unsigned short* dst = VTb + (size_t)(32 * p + lr) * SDIM + ck;
                    *(bf16x8*)(dst) = u0;
                    *(bf16x8*)(dst + 8) = u1;
                }
                __syncthreads();
            }
        }
    } else {
#pragma unroll
        for (int i = 0; i < 4; i++) {
            int r0 = tm + wr + i * 16 + quad * 4;
#pragma unroll
            for (int j = 0; j < 4; j++) {
                int c = tn + wc + j * 16 + l16;
#pragma unroll
                for (int rr = 0; rr < 4; rr++) {
                    int r = r0 + rr;
                    if (MODE == 1 && c > r) continue;  // masked: never read downstream
                    storeC(C, (size_t)r * LDC + c, acc[i][j][rr] * alpha);
                }
            }
        }
    }
}

// ---------- in-place causal softmax on bf16 S ----------
// Reads only chunks with j0 < valid; writes zeros only up to the next 128
// boundary (PV's K clamp guarantees nothing beyond is read).
__global__ __launch_bounds__(256) void softmax_causal(unsigned short* __restrict__ S01,
                                                      unsigned short* __restrict__ S23,
                                                      long long sS) {
    int row = blockIdx.x;
    int b = blockIdx.y;
    unsigned short* srow = (b < 2 ? S01 : S23) + (long long)(b & 1) * sS + (size_t)row * SDIM;
    int tid = threadIdx.x;
    int j0 = tid * 8;
    int valid = row + 1;
    int bound = ((row >> 7) + 1) << 7;   // next multiple of 128 above row
    bool active = j0 < valid;
    __shared__ float red[4];

    float f[8];
    if (active) {
        bf16x8 v8 = *(const bf16x8*)(srow + j0);
#pragma unroll
        for (int i = 0; i < 8; i++) f[i] = bf2f((unsigned short)v8[i]);
    }

    float m = -1e30f;
    if (active) {
#pragma unroll
        for (int i = 0; i < 8; i++) if (j0 + i < valid) m = fmaxf(m, f[i]);
    }
#pragma unroll
    for (int o = 32; o; o >>= 1) m = fmaxf(m, __shfl_xor(m, o, 64));
    if ((tid & 63) == 0) red[tid >> 6] = m;
    __syncthreads();
    m = fmaxf(fmaxf(red[0], red[1]), fmaxf(red[2], red[3]));
    __syncthreads();

    float e[8] = {0.f, 0.f, 0.f, 0.f, 0.f, 0.f, 0.f, 0.f};
    float l = 0.f;
    if (active) {
#pragma unroll
        for (int i = 0; i < 8; i++) {
            e[i] = (j0 + i < valid) ? __expf(f[i] - m) : 0.f;
            l += e[i];
        }
    }
#pragma unroll
    for (int o = 32; o; o >>= 1) l += __shfl_xor(l, o, 64);
    if ((tid & 63) == 0) red[tid >> 6] = l;
    __syncthreads();
    l = red[0] + red[1] + red[2] + red[3];
    float inv = 1.0f / l;

    if (j0 < bound) {
        bf16x8 o8;
#pragma unroll
        for (int i = 0; i < 8; i++) o8[i] = (short)f2bf(e[i] * inv);
        *(bf16x8*)(srow + j0) = o8;
    }
}

// ---------- host ----------
extern "C" void kernel_launch(void* const* d_in, const int* in_sizes, int n_in,
                              void* d_out, int out_size, void* d_ws, size_t ws_size,
                              hipStream_t stream) {
    const float* x  = (const float*)d_in[0];
    const float* Wq = (const float*)d_in[1];
    const float* Wk = (const float*)d_in[2];
    const float* Wv = (const float*)d_in[3];
    float* out = (float*)d_out;

    const size_t MS = (size_t)BDIM * SDIM;        // 8192
    const long long SS = (long long)SDIM * SDIM;  // per-batch score elems
    char* ws = (char*)d_ws;
    size_t off = 0;
    // S01 aliases Xb (Xb dead after QKV GEMM).
    unsigned short* Xb   = (unsigned short*)(ws + off);
    unsigned short* S01  = Xb;                          off += MS * DDIM * 2;           // 16 MB
    unsigned short* WT   = (unsigned short*)(ws + off); off += 3ull * DDIM * PDIM * 2;  // 6 MB
    unsigned short* Q    = (unsigned short*)(ws + off); off += MS * PDIM * 2;           // 16 MB
    unsigned short* Kb   = (unsigned short*)(ws + off); off += MS * PDIM * 2;           // 16 MB
    unsigned short* VT   = (unsigned short*)(ws + off); off += MS * PDIM * 2;           // 16 MB
    unsigned short* S23  = (unsigned short*)(ws + off); off += 2ull * SS * 2;           // 16 MB
    // total ~86 MB

    // 1. fused prep: cast x -> bf16  +  transpose/cast weights
    prep_kernel<<<4096 + 3072, 256, 0, stream>>>(x, Wq, Wk, Wv, Xb, WT);

    // 2. fused QKV projection -> Q, Kb, VT(transposed)   (1536 blocks)
    gemm_bt<DDIM, DDIM, PDIM, DDIM, 0, unsigned short>
        <<<dim3(3 * PDIM / 128, MS / 128, 1), 256, 0, stream>>>(
        Xb, Xb, 0, WT, 0, Q, Q, 0, Kb, VT, 1.0f);

    const long long sQ = (long long)SDIM * PDIM;   // per-batch Q/K/VT stride
    const float alpha = 1.0f / 32.0f;              // 1/sqrt(P)

    // 3. scores: packed lower-triangle grid (136 tiles) x 4 batches
    gemm_bt<PDIM, PDIM, SDIM, PDIM, 1, unsigned short>
        <<<dim3(136, 1, BDIM), 256, 0, stream>>>(
        Q, Q + 2 * sQ, sQ, Kb, sQ, S01, S23, SS, nullptr, nullptr, alpha);

    // 4. in-place softmax (S -> P, bf16)
    softmax_causal<<<dim3(SDIM, BDIM), 256, 0, stream>>>(S01, S23, SS);

    // 5. PV: out_b = P_b @ VT_b^T with causal K clamp
    const long long sOut = (long long)SDIM * PDIM;
    gemm_bt<SDIM, SDIM, PDIM, SDIM, 2, float>
        <<<dim3(PDIM / 128, SDIM / 128, BDIM), 256, 0, stream>>>(
        S01, S23, SS, VT, sQ, out, out + 2 * sOut, sOut, nullptr, nullptr, 1.0f);
}